// Round 5
// baseline (436.974 us; speedup 1.0000x reference)
//
#include <hip/hip_runtime.h>
#include <hip/hip_fp16.h>
#include <math.h>

#define N_NODES 50000
#define N_EDGES 800000
#define N_GRAPHS 512
#define SCAN_NB 196                       // ceil(50000/256)
#define SORTED_CAP 1150000                // 800k + 50k*7 (pad-8)

// workspace byte offsets — every table 256B-aligned so fp16 rows = 1 cache line
#define OFF_HIST    0u
#define OFF_POOLED  200192u
#define OFF_CNTS    331264u
#define OFF_DINV    333312u
#define OFF_OFFS    533504u
#define OFF_CURSOR  733696u
#define OFF_BSUM    933888u
#define OFF_BOFF    934912u
#define OFF_SORTED  935936u
#define OFF_XSH1    5536000u              // 50001*64 halves
#define OFF_XSH2    11936256u             // 50001*64 halves
#define OFF_H1      18336512u             // 50000*64 fp32

// ---- fused: fill sorted with sentinel + histogram of dst ----
__global__ __launch_bounds__(256) void prep(const int* __restrict__ dst, int* __restrict__ hist,
                                            int* __restrict__ sorted) {
    int i = blockIdx.x * 256 + threadIdx.x;
    if (i < SORTED_CAP) sorted[i] = N_NODES;          // sentinel -> zero row
    if (i < N_EDGES) atomicAdd(&hist[dst[i]], 1);
}

// ---- scan phase 1: per-block exclusive scan of padded deg; dinv = rsqrt(1+deg) ----
__global__ __launch_bounds__(256) void scan1(const int* __restrict__ hist, int* __restrict__ offs,
                                             int* __restrict__ bsum, float* __restrict__ dinv) {
    __shared__ int sh[256];
    int t = threadIdx.x;
    int i = blockIdx.x * 256 + t;
    int v = (i < N_NODES) ? hist[i] : 0;
    int pv = (v + 7) & ~7;                 // pad each bucket to multiple of 8
    if (i < N_NODES) dinv[i] = rsqrtf(1.0f + (float)v);
    sh[t] = pv;
    __syncthreads();
    for (int d = 1; d < 256; d <<= 1) {
        int add = (t >= d) ? sh[t - d] : 0;
        __syncthreads();
        sh[t] += add;
        __syncthreads();
    }
    if (i < N_NODES) offs[i] = sh[t] - pv;
    if (t == 255) bsum[blockIdx.x] = sh[255];
}

// ---- scan phase 2 ----
__global__ __launch_bounds__(256) void scan2(const int* __restrict__ bsum, int* __restrict__ boff) {
    __shared__ int sh[256];
    int t = threadIdx.x;
    int v = (t < SCAN_NB) ? bsum[t] : 0;
    sh[t] = v;
    __syncthreads();
    for (int d = 1; d < 256; d <<= 1) {
        int add = (t >= d) ? sh[t - d] : 0;
        __syncthreads();
        sh[t] += add;
        __syncthreads();
    }
    if (t < SCAN_NB) boff[t] = sh[t] - v;
}

// ---- scan phase 3: globalize offsets; init cursor; sentinel row zeroing ----
__global__ __launch_bounds__(256) void scan3(int* __restrict__ offs, const int* __restrict__ boff,
                                             int* __restrict__ cursor, const int* __restrict__ hist,
                                             unsigned short* __restrict__ xsh1,
                                             unsigned short* __restrict__ xsh2) {
    int i = blockIdx.x * 256 + threadIdx.x;
    if (i < N_NODES) {
        int o = offs[i] + boff[blockIdx.x];
        offs[i] = o;
        cursor[i] = o;
        if (i == N_NODES - 1) offs[N_NODES] = o + ((hist[i] + 7) & ~7);
    } else {
        int r = i - N_NODES;               // spare threads zero row 50000 of both tables
        if (r < 64) xsh1[N_NODES * 64 + r] = 0;
        else if (r < 128) xsh2[N_NODES * 64 + (r - 64)] = 0;
    }
}

// ---- reorder edges into padded dst-buckets ----
__global__ __launch_bounds__(256) void reorder(const int* __restrict__ src, const int* __restrict__ dst,
                                               int* __restrict__ cursor, int* __restrict__ sorted, int n) {
    int e = blockIdx.x * 256 + threadIdx.x;
    if (e < n) {
        int d = dst[e];
        int p = atomicAdd(&cursor[d], 1);
        sorted[p] = src[e];
    }
}

// ---- GEMM: xsh = fp16((X @ W) * dinv[row]) ----
template <int K>
__global__ __launch_bounds__(256) void gemm16(const float* __restrict__ X, const float* __restrict__ W,
                                              const float* __restrict__ dinv, __half* __restrict__ xsh) {
    __shared__ float sW[K * 64];
    __shared__ float sX[16][K + 1];
    int tid = threadIdx.x;
    for (int i = tid; i < K * 64; i += 256) sW[i] = W[i];
    int row0 = blockIdx.x * 16;   // 50000 % 16 == 0
    for (int i = tid; i < 16 * K; i += 256) {
        int r = i / K, k = i % K;
        sX[r][k] = X[(row0 + r) * K + k];
    }
    __syncthreads();
    int r = tid >> 4;
    int cg = (tid & 15) * 4;
    int row = row0 + r;
    float a0 = 0, a1 = 0, a2 = 0, a3 = 0;
#pragma unroll 8
    for (int k = 0; k < K; ++k) {
        float xv = sX[r][k];
        float4 w = *(const float4*)&sW[k * 64 + cg];
        a0 += xv * w.x; a1 += xv * w.y; a2 += xv * w.z; a3 += xv * w.w;
    }
    float s = dinv[row];
    __half2 lo = __floats2half2_rn(a0 * s, a1 * s);
    __half2 hi = __floats2half2_rn(a2 * s, a3 * s);
    uint2 pk;
    pk.x = *(const unsigned int*)&lo;
    pk.y = *(const unsigned int*)&hi;
    *(uint2*)&xsh[row * 64 + cg] = pk;
}

// ---- gather: wave/node; lane = (sub=edge slot 0..7, frag=16B row fragment 0..7) ----
// One dwordx4 load per lane -> one instruction fetches 8 whole fp16 rows (8 lines).
template <bool POOL>
__global__ __launch_bounds__(256) void gather8(const __half* __restrict__ xsh,
                                               const int* __restrict__ offs, const int* __restrict__ sorted,
                                               const float* __restrict__ dinv, const float* __restrict__ bias,
                                               float* __restrict__ out, const int* __restrict__ batch,
                                               float* __restrict__ pooled, float* __restrict__ cnts) {
    int node = blockIdx.x * 4 + (threadIdx.x >> 6);   // 12500*4 == 50000 exact
    int lane = threadIdx.x & 63;
    int sub  = lane >> 3;
    int frag = lane & 7;
    int beg = offs[node], end = offs[node + 1];       // multiples of 8
    int nit = (end - beg) >> 3;
    int cur = (nit > 0) ? sorted[beg + sub] : 0;      // issue early
    uint4 sv = *(const uint4*)(xsh + node * 64 + frag * 8);   // self row
    float a0 = 0, a1 = 0, a2 = 0, a3 = 0, a4 = 0, a5 = 0, a6 = 0, a7 = 0;
    {
        const __half2* ph = (const __half2*)&sv;
        float2 f0 = __half22float2(ph[0]), f1 = __half22float2(ph[1]);
        float2 f2 = __half22float2(ph[2]), f3 = __half22float2(ph[3]);
        if (sub == 0) {
            a0 = f0.x; a1 = f0.y; a2 = f1.x; a3 = f1.y;
            a4 = f2.x; a5 = f2.y; a6 = f3.x; a7 = f3.y;
        }
    }
    for (int it = 0; it < nit; ++it) {
        int nxt = (it + 1 < nit) ? sorted[beg + (it + 1) * 8 + sub] : 0;
        uint4 rv = *(const uint4*)(xsh + cur * 64 + frag * 8);
        const __half2* ph = (const __half2*)&rv;
        float2 f0 = __half22float2(ph[0]), f1 = __half22float2(ph[1]);
        float2 f2 = __half22float2(ph[2]), f3 = __half22float2(ph[3]);
        a0 += f0.x; a1 += f0.y; a2 += f1.x; a3 += f1.y;
        a4 += f2.x; a5 += f2.y; a6 += f3.x; a7 += f3.y;
        cur = nxt;
    }
    // reduce across sub (lane bits 3..5); frag stays aligned
    for (int m = 8; m < 64; m <<= 1) {
        a0 += __shfl_xor(a0, m); a1 += __shfl_xor(a1, m);
        a2 += __shfl_xor(a2, m); a3 += __shfl_xor(a3, m);
        a4 += __shfl_xor(a4, m); a5 += __shfl_xor(a5, m);
        a6 += __shfl_xor(a6, m); a7 += __shfl_xor(a7, m);
    }
    if (sub == 0) {
        float d = dinv[node];
        float4 b0 = *(const float4*)(bias + frag * 8);
        float4 b1 = *(const float4*)(bias + frag * 8 + 4);
        float v0 = fmaxf(a0 * d + b0.x, 0.0f);
        float v1 = fmaxf(a1 * d + b0.y, 0.0f);
        float v2 = fmaxf(a2 * d + b0.z, 0.0f);
        float v3 = fmaxf(a3 * d + b0.w, 0.0f);
        float v4 = fmaxf(a4 * d + b1.x, 0.0f);
        float v5 = fmaxf(a5 * d + b1.y, 0.0f);
        float v6 = fmaxf(a6 * d + b1.z, 0.0f);
        float v7 = fmaxf(a7 * d + b1.w, 0.0f);
        if (POOL) {
            int g = batch[node];
            float* p = pooled + g * 64 + frag * 8;
            atomicAdd(p + 0, v0); atomicAdd(p + 1, v1);
            atomicAdd(p + 2, v2); atomicAdd(p + 3, v3);
            atomicAdd(p + 4, v4); atomicAdd(p + 5, v5);
            atomicAdd(p + 6, v6); atomicAdd(p + 7, v7);
            if (frag == 0) atomicAdd(&cnts[g], 1.0f);
        } else {
            float* o = out + node * 64 + frag * 8;
            float4 w0; w0.x = v0; w0.y = v1; w0.z = v2; w0.w = v3;
            float4 w1; w1.x = v4; w1.y = v5; w1.z = v6; w1.w = v7;
            *(float4*)(o) = w0;
            *(float4*)(o + 4) = w1;
        }
    }
}

// ---- head ----
__global__ __launch_bounds__(256) void head(const float* __restrict__ pooled, const float* __restrict__ cnts,
                                            const float* __restrict__ Wfc, const float* __restrict__ bfc,
                                            const int* __restrict__ y, float* __restrict__ out, int n_graphs) {
    int g = blockIdx.x * 256 + threadIdx.x;
    if (g >= n_graphs) return;
    float c = fmaxf(cnts[g], 1.0f);
    float l0 = bfc[0], l1 = bfc[1], l2 = bfc[2], l3 = bfc[3];
#pragma unroll
    for (int k = 0; k < 64; ++k) {
        float p = pooled[g * 64 + k] / c;
        l0 += p * Wfc[k * 4 + 0];
        l1 += p * Wfc[k * 4 + 1];
        l2 += p * Wfc[k * 4 + 2];
        l3 += p * Wfc[k * 4 + 3];
    }
    float m = fmaxf(fmaxf(l0, l1), fmaxf(l2, l3));
    float s = expf(l0 - m) + expf(l1 - m) + expf(l2 - m) + expf(l3 - m);
    float lse = m + logf(s);
    out[g * 4 + 0] = l0 - lse;
    out[g * 4 + 1] = l1 - lse;
    out[g * 4 + 2] = l2 - lse;
    out[g * 4 + 3] = l3 - lse;
    out[n_graphs * 4 + g] = (float)y[g];
}

extern "C" void kernel_launch(void* const* d_in, const int* in_sizes, int n_in,
                              void* d_out, int out_size, void* d_ws, size_t ws_size,
                              hipStream_t stream) {
    const float* x     = (const float*)d_in[0];
    const int*   ei    = (const int*)d_in[1];
    const int*   batch = (const int*)d_in[2];
    const int*   y     = (const int*)d_in[3];
    const float* W1    = (const float*)d_in[4];
    const float* b1    = (const float*)d_in[5];
    const float* W2    = (const float*)d_in[6];
    const float* b2    = (const float*)d_in[7];
    const float* Wfc   = (const float*)d_in[8];
    const float* bfc   = (const float*)d_in[9];
    float* out = (float*)d_out;

    const int* src = ei;
    const int* dst = ei + N_EDGES;

    char* wsb = (char*)d_ws;
    int*    hist   = (int*)(wsb + OFF_HIST);
    float*  pooled = (float*)(wsb + OFF_POOLED);
    float*  cnts   = (float*)(wsb + OFF_CNTS);
    float*  dinv   = (float*)(wsb + OFF_DINV);
    int*    offs   = (int*)(wsb + OFF_OFFS);
    int*    cursor = (int*)(wsb + OFF_CURSOR);
    int*    bsum   = (int*)(wsb + OFF_BSUM);
    int*    boff   = (int*)(wsb + OFF_BOFF);
    int*    sorted = (int*)(wsb + OFF_SORTED);
    __half* xsh1   = (__half*)(wsb + OFF_XSH1);
    __half* xsh2   = (__half*)(wsb + OFF_XSH2);
    float*  h1     = (float*)(wsb + OFF_H1);

    hipMemsetAsync(wsb, 0, OFF_CNTS + 2048u, stream);          // hist+pooled+cnts

    prep<<<(SORTED_CAP + 255) / 256, 256, 0, stream>>>(dst, hist, sorted);
    scan1<<<SCAN_NB, 256, 0, stream>>>(hist, offs, bsum, dinv);
    scan2<<<1, 256, 0, stream>>>(bsum, boff);
    scan3<<<SCAN_NB, 256, 0, stream>>>(offs, boff, cursor, hist,
                                       (unsigned short*)xsh1, (unsigned short*)xsh2);
    reorder<<<N_EDGES / 256, 256, 0, stream>>>(src, dst, cursor, sorted, N_EDGES);

    // layer 1: 128 -> 64
    gemm16<128><<<N_NODES / 16, 256, 0, stream>>>(x, W1, dinv, xsh1);
    gather8<false><<<N_NODES / 4, 256, 0, stream>>>(xsh1, offs, sorted, dinv, b1, h1,
                                                    nullptr, nullptr, nullptr);
    // layer 2: 64 -> 64 (+ pool)
    gemm16<64><<<N_NODES / 16, 256, 0, stream>>>(h1, W2, dinv, xsh2);
    gather8<true><<<N_NODES / 4, 256, 0, stream>>>(xsh2, offs, sorted, dinv, b2, nullptr,
                                                   batch, pooled, cnts);

    head<<<(N_GRAPHS + 255) / 256, 256, 0, stream>>>(pooled, cnts, Wfc, bfc, y, out, N_GRAPHS);
}

// Round 6
// 281.285 us; speedup vs baseline: 1.5535x; 1.5535x over previous
//
#include <hip/hip_runtime.h>
#include <hip/hip_fp16.h>
#include <math.h>

#define N_NODES 50000
#define N_EDGES 800000
#define N_GRAPHS 512
#define SCAN_NB 196                       // ceil(50000/256)
#define SORTED_CAP 1150000                // 800k + 50k*7 (pad-8)

// workspace byte offsets — every table 256B-aligned so fp16 rows = 1 cache line
#define OFF_HIST    0u
#define OFF_DINV    333312u
#define OFF_OFFS    533504u
#define OFF_CURSOR  733696u
#define OFF_BSUM    933888u
#define OFF_BOFF    934912u
#define OFF_SORTED  935936u
#define OFF_XSH1    5536000u              // 50001*64 halves
#define OFF_XSH2    11936256u             // 50001*64 halves
#define OFF_H1      18336512u             // 50000*64 fp32 (h1, later reused as h2)

// ---- fused: fill sorted with sentinel + histogram of dst ----
__global__ __launch_bounds__(256) void prep(const int* __restrict__ dst, int* __restrict__ hist,
                                            int* __restrict__ sorted) {
    int i = blockIdx.x * 256 + threadIdx.x;
    if (i < SORTED_CAP) sorted[i] = N_NODES;          // sentinel -> zero row
    if (i < N_EDGES) atomicAdd(&hist[dst[i]], 1);
}

// ---- scan phase 1: per-block exclusive scan of padded deg; dinv = rsqrt(1+deg) ----
__global__ __launch_bounds__(256) void scan1(const int* __restrict__ hist, int* __restrict__ offs,
                                             int* __restrict__ bsum, float* __restrict__ dinv) {
    __shared__ int sh[256];
    int t = threadIdx.x;
    int i = blockIdx.x * 256 + t;
    int v = (i < N_NODES) ? hist[i] : 0;
    int pv = (v + 7) & ~7;                 // pad each bucket to multiple of 8
    if (i < N_NODES) dinv[i] = rsqrtf(1.0f + (float)v);
    sh[t] = pv;
    __syncthreads();
    for (int d = 1; d < 256; d <<= 1) {
        int add = (t >= d) ? sh[t - d] : 0;
        __syncthreads();
        sh[t] += add;
        __syncthreads();
    }
    if (i < N_NODES) offs[i] = sh[t] - pv;
    if (t == 255) bsum[blockIdx.x] = sh[255];
}

// ---- scan phase 2 ----
__global__ __launch_bounds__(256) void scan2(const int* __restrict__ bsum, int* __restrict__ boff) {
    __shared__ int sh[256];
    int t = threadIdx.x;
    int v = (t < SCAN_NB) ? bsum[t] : 0;
    sh[t] = v;
    __syncthreads();
    for (int d = 1; d < 256; d <<= 1) {
        int add = (t >= d) ? sh[t - d] : 0;
        __syncthreads();
        sh[t] += add;
        __syncthreads();
    }
    if (t < SCAN_NB) boff[t] = sh[t] - v;
}

// ---- scan phase 3: globalize offsets; init cursor; sentinel row zeroing ----
__global__ __launch_bounds__(256) void scan3(int* __restrict__ offs, const int* __restrict__ boff,
                                             int* __restrict__ cursor, const int* __restrict__ hist,
                                             unsigned short* __restrict__ xsh1,
                                             unsigned short* __restrict__ xsh2) {
    int i = blockIdx.x * 256 + threadIdx.x;
    if (i < N_NODES) {
        int o = offs[i] + boff[blockIdx.x];
        offs[i] = o;
        cursor[i] = o;
        if (i == N_NODES - 1) offs[N_NODES] = o + ((hist[i] + 7) & ~7);
    } else {
        int r = i - N_NODES;               // spare threads zero row 50000 of both tables
        if (r < 64) xsh1[N_NODES * 64 + r] = 0;
        else if (r < 128) xsh2[N_NODES * 64 + (r - 64)] = 0;
    }
}

// ---- reorder edges into padded dst-buckets ----
__global__ __launch_bounds__(256) void reorder(const int* __restrict__ src, const int* __restrict__ dst,
                                               int* __restrict__ cursor, int* __restrict__ sorted, int n) {
    int e = blockIdx.x * 256 + threadIdx.x;
    if (e < n) {
        int d = dst[e];
        int p = atomicAdd(&cursor[d], 1);
        sorted[p] = src[e];
    }
}

// ---- GEMM: xsh = fp16((X @ W) * dinv[row]) ----
template <int K>
__global__ __launch_bounds__(256) void gemm16(const float* __restrict__ X, const float* __restrict__ W,
                                              const float* __restrict__ dinv, __half* __restrict__ xsh) {
    __shared__ float sW[K * 64];
    __shared__ float sX[16][K + 1];
    int tid = threadIdx.x;
    for (int i = tid; i < K * 64; i += 256) sW[i] = W[i];
    int row0 = blockIdx.x * 16;   // 50000 % 16 == 0
    for (int i = tid; i < 16 * K; i += 256) {
        int r = i / K, k = i % K;
        sX[r][k] = X[(row0 + r) * K + k];
    }
    __syncthreads();
    int r = tid >> 4;
    int cg = (tid & 15) * 4;
    int row = row0 + r;
    float a0 = 0, a1 = 0, a2 = 0, a3 = 0;
#pragma unroll 8
    for (int k = 0; k < K; ++k) {
        float xv = sX[r][k];
        float4 w = *(const float4*)&sW[k * 64 + cg];
        a0 += xv * w.x; a1 += xv * w.y; a2 += xv * w.z; a3 += xv * w.w;
    }
    float s = dinv[row];
    __half2 lo = __floats2half2_rn(a0 * s, a1 * s);
    __half2 hi = __floats2half2_rn(a2 * s, a3 * s);
    uint2 pk;
    pk.x = *(const unsigned int*)&lo;
    pk.y = *(const unsigned int*)&hi;
    *(uint2*)&xsh[row * 64 + cg] = pk;
}

// ---- gather: wave/node; lane = (sub 0..7, frag 0..7); 2 row-load instrs in flight ----
__global__ __launch_bounds__(256) void gather8(const __half* __restrict__ xsh,
                                               const int* __restrict__ offs, const int* __restrict__ sorted,
                                               const float* __restrict__ dinv, const float* __restrict__ bias,
                                               float* __restrict__ out) {
    int node = blockIdx.x * 4 + (threadIdx.x >> 6);   // 12500*4 == 50000 exact
    int lane = threadIdx.x & 63;
    int sub  = lane >> 3;
    int frag = lane & 7;
    int beg = offs[node], end = offs[node + 1];       // multiples of 8
    int nit = (end - beg) >> 3;
    int cur0 = (nit > 0) ? sorted[beg + sub] : N_NODES;
    int cur1 = (nit > 1) ? sorted[beg + 8 + sub] : N_NODES;
    uint4 sv = *(const uint4*)(xsh + node * 64 + frag * 8);   // self row
    float a0 = 0, a1 = 0, a2 = 0, a3 = 0, a4 = 0, a5 = 0, a6 = 0, a7 = 0;
    {
        const __half2* ph = (const __half2*)&sv;
        float2 f0 = __half22float2(ph[0]), f1 = __half22float2(ph[1]);
        float2 f2 = __half22float2(ph[2]), f3 = __half22float2(ph[3]);
        if (sub == 0) {
            a0 = f0.x; a1 = f0.y; a2 = f1.x; a3 = f1.y;
            a4 = f2.x; a5 = f2.y; a6 = f3.x; a7 = f3.y;
        }
    }
    for (int it = 0; it < nit; it += 2) {
        // both row loads issued before either is consumed -> 16 lines in flight
        uint4 r0 = *(const uint4*)(xsh + cur0 * 64 + frag * 8);
        uint4 r1 = *(const uint4*)(xsh + cur1 * 64 + frag * 8);
        int n0 = (it + 2 < nit) ? sorted[beg + (it + 2) * 8 + sub] : N_NODES;
        int n1 = (it + 3 < nit) ? sorted[beg + (it + 3) * 8 + sub] : N_NODES;
        const __half2* p0 = (const __half2*)&r0;
        float2 g0 = __half22float2(p0[0]), g1 = __half22float2(p0[1]);
        float2 g2 = __half22float2(p0[2]), g3 = __half22float2(p0[3]);
        a0 += g0.x; a1 += g0.y; a2 += g1.x; a3 += g1.y;
        a4 += g2.x; a5 += g2.y; a6 += g3.x; a7 += g3.y;
        const __half2* p1 = (const __half2*)&r1;
        float2 h0 = __half22float2(p1[0]), h1 = __half22float2(p1[1]);
        float2 h2 = __half22float2(p1[2]), h3 = __half22float2(p1[3]);
        a0 += h0.x; a1 += h0.y; a2 += h1.x; a3 += h1.y;
        a4 += h2.x; a5 += h2.y; a6 += h3.x; a7 += h3.y;
        cur0 = n0; cur1 = n1;
    }
    // reduce across sub (lane bits 3..5); frag stays aligned
    for (int m = 8; m < 64; m <<= 1) {
        a0 += __shfl_xor(a0, m); a1 += __shfl_xor(a1, m);
        a2 += __shfl_xor(a2, m); a3 += __shfl_xor(a3, m);
        a4 += __shfl_xor(a4, m); a5 += __shfl_xor(a5, m);
        a6 += __shfl_xor(a6, m); a7 += __shfl_xor(a7, m);
    }
    if (sub == 0) {
        float d = dinv[node];
        float4 b0 = *(const float4*)(bias + frag * 8);
        float4 b1 = *(const float4*)(bias + frag * 8 + 4);
        float4 w0, w1;
        w0.x = fmaxf(a0 * d + b0.x, 0.0f);
        w0.y = fmaxf(a1 * d + b0.y, 0.0f);
        w0.z = fmaxf(a2 * d + b0.z, 0.0f);
        w0.w = fmaxf(a3 * d + b0.w, 0.0f);
        w1.x = fmaxf(a4 * d + b1.x, 0.0f);
        w1.y = fmaxf(a5 * d + b1.y, 0.0f);
        w1.z = fmaxf(a6 * d + b1.z, 0.0f);
        w1.w = fmaxf(a7 * d + b1.w, 0.0f);
        float* o = out + node * 64 + frag * 8;
        *(float4*)(o) = w0;
        *(float4*)(o + 4) = w1;
    }
}

// ---- fused pool (segmented mean over sorted batch) + fc head + log_softmax ----
__device__ __forceinline__ int lower_bound(const int* __restrict__ a, int n, int v) {
    int lo = 0, hi = n;
    while (lo < hi) { int m = (lo + hi) >> 1; if (a[m] < v) lo = m + 1; else hi = m; }
    return lo;
}

__global__ __launch_bounds__(256) void pool_head(const float* __restrict__ h2,
                                                 const int* __restrict__ batch,
                                                 const float* __restrict__ Wfc, const float* __restrict__ bfc,
                                                 const int* __restrict__ y, float* __restrict__ out) {
    __shared__ int s_beg, s_end;
    __shared__ float sh[4][64];
    __shared__ float pl[64];
    __shared__ float lg[4];
    int g = blockIdx.x;
    int t = threadIdx.x;
    if (t == 0) s_beg = lower_bound(batch, N_NODES, g);
    if (t == 1) s_end = lower_bound(batch, N_NODES, g + 1);
    __syncthreads();
    int beg = s_beg, end = s_end;
    int f = t & 63, seg = t >> 6;
    float s = 0.0f;
    for (int r = beg + seg; r < end; r += 4) s += h2[r * 64 + f];
    sh[seg][f] = s;
    __syncthreads();
    if (t < 64) {
        float p = sh[0][t] + sh[1][t] + sh[2][t] + sh[3][t];
        pl[t] = p / fmaxf((float)(end - beg), 1.0f);
    }
    __syncthreads();
    if (t < 4) {
        float l = bfc[t];
#pragma unroll
        for (int k = 0; k < 64; ++k) l += pl[k] * Wfc[k * 4 + t];
        lg[t] = l;
    }
    __syncthreads();
    if (t == 0) {
        float l0 = lg[0], l1 = lg[1], l2 = lg[2], l3 = lg[3];
        float m = fmaxf(fmaxf(l0, l1), fmaxf(l2, l3));
        float ss = expf(l0 - m) + expf(l1 - m) + expf(l2 - m) + expf(l3 - m);
        float lse = m + logf(ss);
        out[g * 4 + 0] = l0 - lse;
        out[g * 4 + 1] = l1 - lse;
        out[g * 4 + 2] = l2 - lse;
        out[g * 4 + 3] = l3 - lse;
        out[N_GRAPHS * 4 + g] = (float)y[g];
    }
}

extern "C" void kernel_launch(void* const* d_in, const int* in_sizes, int n_in,
                              void* d_out, int out_size, void* d_ws, size_t ws_size,
                              hipStream_t stream) {
    const float* x     = (const float*)d_in[0];
    const int*   ei    = (const int*)d_in[1];
    const int*   batch = (const int*)d_in[2];
    const int*   y     = (const int*)d_in[3];
    const float* W1    = (const float*)d_in[4];
    const float* b1    = (const float*)d_in[5];
    const float* W2    = (const float*)d_in[6];
    const float* b2    = (const float*)d_in[7];
    const float* Wfc   = (const float*)d_in[8];
    const float* bfc   = (const float*)d_in[9];
    float* out = (float*)d_out;

    const int* src = ei;
    const int* dst = ei + N_EDGES;

    char* wsb = (char*)d_ws;
    int*    hist   = (int*)(wsb + OFF_HIST);
    float*  dinv   = (float*)(wsb + OFF_DINV);
    int*    offs   = (int*)(wsb + OFF_OFFS);
    int*    cursor = (int*)(wsb + OFF_CURSOR);
    int*    bsum   = (int*)(wsb + OFF_BSUM);
    int*    boff   = (int*)(wsb + OFF_BOFF);
    int*    sorted = (int*)(wsb + OFF_SORTED);
    __half* xsh1   = (__half*)(wsb + OFF_XSH1);
    __half* xsh2   = (__half*)(wsb + OFF_XSH2);
    float*  h1     = (float*)(wsb + OFF_H1);   // layer-1 output; reused as h2 after gemm2

    hipMemsetAsync(hist, 0, 200000u, stream);

    prep<<<(SORTED_CAP + 255) / 256, 256, 0, stream>>>(dst, hist, sorted);
    scan1<<<SCAN_NB, 256, 0, stream>>>(hist, offs, bsum, dinv);
    scan2<<<1, 256, 0, stream>>>(bsum, boff);
    scan3<<<SCAN_NB, 256, 0, stream>>>(offs, boff, cursor, hist,
                                       (unsigned short*)xsh1, (unsigned short*)xsh2);
    reorder<<<N_EDGES / 256, 256, 0, stream>>>(src, dst, cursor, sorted, N_EDGES);

    // layer 1: 128 -> 64
    gemm16<128><<<N_NODES / 16, 256, 0, stream>>>(x, W1, dinv, xsh1);
    gather8<<<N_NODES / 4, 256, 0, stream>>>(xsh1, offs, sorted, dinv, b1, h1);
    // layer 2: 64 -> 64
    gemm16<64><<<N_NODES / 16, 256, 0, stream>>>(h1, W2, dinv, xsh2);
    gather8<<<N_NODES / 4, 256, 0, stream>>>(xsh2, offs, sorted, dinv, b2, h1);  // h1 -> h2

    // pool + head (batch sorted -> contiguous segments; no atomics)
    pool_head<<<N_GRAPHS, 256, 0, stream>>>(h1, batch, Wfc, bfc, y, out);
}

// Round 7
// 279.524 us; speedup vs baseline: 1.5633x; 1.0063x over previous
//
#include <hip/hip_runtime.h>
#include <hip/hip_fp16.h>
#include <math.h>

#define N_NODES 50000
#define N_EDGES 800000
#define N_GRAPHS 512
#define SCAN_NB 196                       // ceil(50000/256)
#define SENT N_NODES

// workspace byte offsets — every table 256B-aligned; fp16 rows = exactly 1 line
#define OFF_HIST    0u                    // 50000 ints
#define OFF_DINV    200192u               // 50000 floats
#define OFF_OFFS    400384u               // 50001 ints
#define OFF_CURSOR  600576u               // 50000 ints
#define OFF_BSUM    800768u               // 256 ints
#define OFF_BOFF    801792u               // 256 ints
#define OFF_SORTED  803840u               // 1150000 ints (800k + 50k*7 pad-8)
#define OFF_XSH1    5403904u              // 50001*64 halves
#define OFF_XSH2    11804160u             // 50001*64 halves
#define OFF_H2      18204416u             // 50000*64 fp32

// ---- histogram of dst ----
__global__ __launch_bounds__(256) void prep(const int* __restrict__ dst, int* __restrict__ hist) {
    int e = blockIdx.x * 256 + threadIdx.x;
    if (e < N_EDGES) atomicAdd(&hist[dst[e]], 1);
}

// ---- scan phase 1: per-block exclusive scan of padded deg; dinv = rsqrt(1+deg) ----
__global__ __launch_bounds__(256) void scan1(const int* __restrict__ hist, int* __restrict__ offs,
                                             int* __restrict__ bsum, float* __restrict__ dinv) {
    __shared__ int sh[256];
    int t = threadIdx.x;
    int i = blockIdx.x * 256 + t;
    int v = (i < N_NODES) ? hist[i] : 0;
    int pv = (v + 7) & ~7;                 // pad each bucket to multiple of 8
    if (i < N_NODES) dinv[i] = rsqrtf(1.0f + (float)v);
    sh[t] = pv;
    __syncthreads();
    for (int d = 1; d < 256; d <<= 1) {
        int add = (t >= d) ? sh[t - d] : 0;
        __syncthreads();
        sh[t] += add;
        __syncthreads();
    }
    if (i < N_NODES) offs[i] = sh[t] - pv;
    if (t == 255) bsum[blockIdx.x] = sh[255];
}

// ---- scan phase 2 ----
__global__ __launch_bounds__(256) void scan2(const int* __restrict__ bsum, int* __restrict__ boff) {
    __shared__ int sh[256];
    int t = threadIdx.x;
    int v = (t < SCAN_NB) ? bsum[t] : 0;
    sh[t] = v;
    __syncthreads();
    for (int d = 1; d < 256; d <<= 1) {
        int add = (t >= d) ? sh[t - d] : 0;
        __syncthreads();
        sh[t] += add;
        __syncthreads();
    }
    if (t < SCAN_NB) boff[t] = sh[t] - v;
}

// ---- scan phase 3: globalize offsets; cursor; pad-slot sentinels; zero sentinel rows ----
__global__ __launch_bounds__(256) void scan3(int* __restrict__ offs, const int* __restrict__ boff,
                                             int* __restrict__ cursor, const int* __restrict__ hist,
                                             int* __restrict__ sorted,
                                             unsigned short* __restrict__ xsh1,
                                             unsigned short* __restrict__ xsh2) {
    int i = blockIdx.x * 256 + threadIdx.x;
    if (i < N_NODES) {
        int deg = hist[i];
        int o = offs[i] + boff[blockIdx.x];
        offs[i] = o;
        cursor[i] = o;
        int pd = (deg + 7) & ~7;
        for (int p = o + deg; p < o + pd; ++p) sorted[p] = SENT;   // pad slots only
        if (i == N_NODES - 1) offs[N_NODES] = o + pd;
    } else {
        int r = i - N_NODES;               // spare threads zero row 50000 of both tables
        if (r < 64) xsh1[N_NODES * 64 + r] = 0;
        else if (r < 128) xsh2[N_NODES * 64 + (r - 64)] = 0;
    }
}

// ---- reorder edges into padded dst-buckets ----
__global__ __launch_bounds__(256) void reorder(const int* __restrict__ src, const int* __restrict__ dst,
                                               int* __restrict__ cursor, int* __restrict__ sorted, int n) {
    int e = blockIdx.x * 256 + threadIdx.x;
    if (e < n) {
        int d = dst[e];
        int p = atomicAdd(&cursor[d], 1);
        sorted[p] = src[e];
    }
}

// ---- GEMM (layer 1 only): xsh1 = fp16((X @ W1) * dinv[row]), K=128 ----
__global__ __launch_bounds__(256) void gemm1(const float* __restrict__ X, const float* __restrict__ W,
                                             const float* __restrict__ dinv, __half* __restrict__ xsh) {
    __shared__ float sW[128 * 64];
    __shared__ float sX[16 * 132];         // stride 132: 16B-aligned + bank-spread
    int tid = threadIdx.x;
    {   // stage W: 8192 floats = 2048 float4
        const float4* ws = (const float4*)W;
        float4* wd = (float4*)sW;
        for (int i = tid; i < 2048; i += 256) wd[i] = ws[i];
    }
    int row0 = blockIdx.x * 16;            // 50000 % 16 == 0
    {   // stage X: 16 rows x 128 = 512 float4
        const float4* xs = (const float4*)(X + row0 * 128);
        for (int i = tid; i < 512; i += 256) {
            int r = i >> 5, q = i & 31;    // 32 float4 per row
            *(float4*)&sX[r * 132 + 4 * q] = xs[r * 32 + q];
        }
    }
    __syncthreads();
    int r = tid >> 4;
    int cg = (tid & 15) * 4;
    int row = row0 + r;
    float a0 = 0, a1 = 0, a2 = 0, a3 = 0;
#pragma unroll 8
    for (int k = 0; k < 128; ++k) {
        float xv = sX[r * 132 + k];
        float4 w = *(const float4*)&sW[k * 64 + cg];
        a0 += xv * w.x; a1 += xv * w.y; a2 += xv * w.z; a3 += xv * w.w;
    }
    float s = dinv[row];
    __half2 lo = __floats2half2_rn(a0 * s, a1 * s);
    __half2 hi = __floats2half2_rn(a2 * s, a3 * s);
    uint2 pk;
    pk.x = *(const unsigned int*)&lo;
    pk.y = *(const unsigned int*)&hi;
    *(uint2*)&xsh[row * 64 + cg] = pk;
}

// ---- gather: wave/node; lane=(sub 0..7, frag 0..7); 4 row-load instrs in flight ----
// FUSE: epilogue multiplies the finished h-row by W2 (LDS) and emits fp16 xs2 directly.
template <bool FUSE>
__global__ __launch_bounds__(256) void gather_f(const __half* __restrict__ xsh,
                                                const int* __restrict__ offs, const int* __restrict__ sorted,
                                                const float* __restrict__ dinv, const float* __restrict__ bias,
                                                const float* __restrict__ W2, __half* __restrict__ xout,
                                                float* __restrict__ fout) {
    __shared__ float sW2[FUSE ? 64 * 64 : 4];
    __shared__ float sH[FUSE ? 4 : 1][64];
    if (FUSE) {
        const float4* ws = (const float4*)W2;
        float4* wd = (float4*)sW2;
        for (int i = threadIdx.x; i < 1024; i += 256) wd[i] = ws[i];
    }
    int node = blockIdx.x * 4 + (threadIdx.x >> 6);   // 12500*4 == 50000 exact
    int lane = threadIdx.x & 63;
    int sub  = lane >> 3;
    int frag = lane & 7;
    int beg = offs[node], end = offs[node + 1];       // multiples of 8
    int nit = (end - beg) >> 3;
    const int* sb = sorted + beg + sub;
    int i0 = (0 < nit) ? sb[0]  : SENT;
    int i1 = (1 < nit) ? sb[8]  : SENT;
    int i2 = (2 < nit) ? sb[16] : SENT;
    int i3 = (3 < nit) ? sb[24] : SENT;
    uint4 sv = *(const uint4*)(xsh + node * 64 + frag * 8);   // self row
    float a0 = 0, a1 = 0, a2 = 0, a3 = 0, a4 = 0, a5 = 0, a6 = 0, a7 = 0;
    {
        const __half2* ph = (const __half2*)&sv;
        float2 f0 = __half22float2(ph[0]), f1 = __half22float2(ph[1]);
        float2 f2 = __half22float2(ph[2]), f3 = __half22float2(ph[3]);
        if (sub == 0) {
            a0 = f0.x; a1 = f0.y; a2 = f1.x; a3 = f1.y;
            a4 = f2.x; a5 = f2.y; a6 = f3.x; a7 = f3.y;
        }
    }
    for (int it = 0; it < nit; it += 4) {
        // 4 row loads issued back-to-back -> up to 32 lines in flight per wave
        uint4 r0 = *(const uint4*)(xsh + i0 * 64 + frag * 8);
        uint4 r1 = *(const uint4*)(xsh + i1 * 64 + frag * 8);
        uint4 r2 = *(const uint4*)(xsh + i2 * 64 + frag * 8);
        uint4 r3 = *(const uint4*)(xsh + i3 * 64 + frag * 8);
        const int* nb = sb + (it + 4) * 8;
        i0 = (it + 4 < nit) ? nb[0]  : SENT;
        i1 = (it + 5 < nit) ? nb[8]  : SENT;
        i2 = (it + 6 < nit) ? nb[16] : SENT;
        i3 = (it + 7 < nit) ? nb[24] : SENT;
        const __half2* p0 = (const __half2*)&r0;
        const __half2* p1 = (const __half2*)&r1;
        const __half2* p2 = (const __half2*)&r2;
        const __half2* p3 = (const __half2*)&r3;
        float2 g0, g1, g2, g3;
        g0 = __half22float2(p0[0]); g1 = __half22float2(p0[1]);
        g2 = __half22float2(p0[2]); g3 = __half22float2(p0[3]);
        a0 += g0.x; a1 += g0.y; a2 += g1.x; a3 += g1.y;
        a4 += g2.x; a5 += g2.y; a6 += g3.x; a7 += g3.y;
        g0 = __half22float2(p1[0]); g1 = __half22float2(p1[1]);
        g2 = __half22float2(p1[2]); g3 = __half22float2(p1[3]);
        a0 += g0.x; a1 += g0.y; a2 += g1.x; a3 += g1.y;
        a4 += g2.x; a5 += g2.y; a6 += g3.x; a7 += g3.y;
        g0 = __half22float2(p2[0]); g1 = __half22float2(p2[1]);
        g2 = __half22float2(p2[2]); g3 = __half22float2(p2[3]);
        a0 += g0.x; a1 += g0.y; a2 += g1.x; a3 += g1.y;
        a4 += g2.x; a5 += g2.y; a6 += g3.x; a7 += g3.y;
        g0 = __half22float2(p3[0]); g1 = __half22float2(p3[1]);
        g2 = __half22float2(p3[2]); g3 = __half22float2(p3[3]);
        a0 += g0.x; a1 += g0.y; a2 += g1.x; a3 += g1.y;
        a4 += g2.x; a5 += g2.y; a6 += g3.x; a7 += g3.y;
    }
    // reduce across sub (lane bits 3..5); frag stays aligned
    for (int m = 8; m < 64; m <<= 1) {
        a0 += __shfl_xor(a0, m); a1 += __shfl_xor(a1, m);
        a2 += __shfl_xor(a2, m); a3 += __shfl_xor(a3, m);
        a4 += __shfl_xor(a4, m); a5 += __shfl_xor(a5, m);
        a6 += __shfl_xor(a6, m); a7 += __shfl_xor(a7, m);
    }
    float d = dinv[node];
    if (FUSE) {
        int wv = threadIdx.x >> 6;
        if (sub == 0) {
            float4 b0 = *(const float4*)(bias + frag * 8);
            float4 b1 = *(const float4*)(bias + frag * 8 + 4);
            float4 h0, h1;
            h0.x = fmaxf(a0 * d + b0.x, 0.0f);
            h0.y = fmaxf(a1 * d + b0.y, 0.0f);
            h0.z = fmaxf(a2 * d + b0.z, 0.0f);
            h0.w = fmaxf(a3 * d + b0.w, 0.0f);
            h1.x = fmaxf(a4 * d + b1.x, 0.0f);
            h1.y = fmaxf(a5 * d + b1.y, 0.0f);
            h1.z = fmaxf(a6 * d + b1.z, 0.0f);
            h1.w = fmaxf(a7 * d + b1.w, 0.0f);
            *(float4*)&sH[wv][frag * 8]     = h0;
            *(float4*)&sH[wv][frag * 8 + 4] = h1;
        }
        __syncthreads();
        float o = 0.0f;
#pragma unroll 8
        for (int k = 0; k < 64; ++k) o += sH[wv][k] * sW2[k * 64 + lane];
        xout[node * 64 + lane] = __float2half(o * d);   // xs2 = (h1 @ W2) * dinv[node]
    } else {
        if (sub == 0) {
            float4 b0 = *(const float4*)(bias + frag * 8);
            float4 b1 = *(const float4*)(bias + frag * 8 + 4);
            float4 w0, w1;
            w0.x = fmaxf(a0 * d + b0.x, 0.0f);
            w0.y = fmaxf(a1 * d + b0.y, 0.0f);
            w0.z = fmaxf(a2 * d + b0.z, 0.0f);
            w0.w = fmaxf(a3 * d + b0.w, 0.0f);
            w1.x = fmaxf(a4 * d + b1.x, 0.0f);
            w1.y = fmaxf(a5 * d + b1.y, 0.0f);
            w1.z = fmaxf(a6 * d + b1.z, 0.0f);
            w1.w = fmaxf(a7 * d + b1.w, 0.0f);
            float* o = fout + node * 64 + frag * 8;
            *(float4*)(o) = w0;
            *(float4*)(o + 4) = w1;
        }
    }
}

// ---- fused pool (segmented mean over sorted batch) + fc head + log_softmax ----
__device__ __forceinline__ int lower_bound(const int* __restrict__ a, int n, int v) {
    int lo = 0, hi = n;
    while (lo < hi) { int m = (lo + hi) >> 1; if (a[m] < v) lo = m + 1; else hi = m; }
    return lo;
}

__global__ __launch_bounds__(256) void pool_head(const float* __restrict__ h2,
                                                 const int* __restrict__ batch,
                                                 const float* __restrict__ Wfc, const float* __restrict__ bfc,
                                                 const int* __restrict__ y, float* __restrict__ out) {
    __shared__ int s_beg, s_end;
    __shared__ float sh[4][64];
    __shared__ float pl[64];
    __shared__ float lg[4];
    int g = blockIdx.x;
    int t = threadIdx.x;
    if (t == 0) s_beg = lower_bound(batch, N_NODES, g);
    if (t == 1) s_end = lower_bound(batch, N_NODES, g + 1);
    __syncthreads();
    int beg = s_beg, end = s_end;
    int f = t & 63, seg = t >> 6;
    float s = 0.0f;
    for (int r = beg + seg; r < end; r += 4) s += h2[r * 64 + f];
    sh[seg][f] = s;
    __syncthreads();
    if (t < 64) {
        float p = sh[0][t] + sh[1][t] + sh[2][t] + sh[3][t];
        pl[t] = p / fmaxf((float)(end - beg), 1.0f);
    }
    __syncthreads();
    if (t < 4) {
        float l = bfc[t];
#pragma unroll
        for (int k = 0; k < 64; ++k) l += pl[k] * Wfc[k * 4 + t];
        lg[t] = l;
    }
    __syncthreads();
    if (t == 0) {
        float l0 = lg[0], l1 = lg[1], l2 = lg[2], l3 = lg[3];
        float m = fmaxf(fmaxf(l0, l1), fmaxf(l2, l3));
        float ss = expf(l0 - m) + expf(l1 - m) + expf(l2 - m) + expf(l3 - m);
        float lse = m + logf(ss);
        out[g * 4 + 0] = l0 - lse;
        out[g * 4 + 1] = l1 - lse;
        out[g * 4 + 2] = l2 - lse;
        out[g * 4 + 3] = l3 - lse;
        out[N_GRAPHS * 4 + g] = (float)y[g];
    }
}

extern "C" void kernel_launch(void* const* d_in, const int* in_sizes, int n_in,
                              void* d_out, int out_size, void* d_ws, size_t ws_size,
                              hipStream_t stream) {
    const float* x     = (const float*)d_in[0];
    const int*   ei    = (const int*)d_in[1];
    const int*   batch = (const int*)d_in[2];
    const int*   y     = (const int*)d_in[3];
    const float* W1    = (const float*)d_in[4];
    const float* b1    = (const float*)d_in[5];
    const float* W2    = (const float*)d_in[6];
    const float* b2    = (const float*)d_in[7];
    const float* Wfc   = (const float*)d_in[8];
    const float* bfc   = (const float*)d_in[9];
    float* out = (float*)d_out;

    const int* src = ei;
    const int* dst = ei + N_EDGES;

    char* wsb = (char*)d_ws;
    int*    hist   = (int*)(wsb + OFF_HIST);
    float*  dinv   = (float*)(wsb + OFF_DINV);
    int*    offs   = (int*)(wsb + OFF_OFFS);
    int*    cursor = (int*)(wsb + OFF_CURSOR);
    int*    bsum   = (int*)(wsb + OFF_BSUM);
    int*    boff   = (int*)(wsb + OFF_BOFF);
    int*    sorted = (int*)(wsb + OFF_SORTED);
    __half* xsh1   = (__half*)(wsb + OFF_XSH1);
    __half* xsh2   = (__half*)(wsb + OFF_XSH2);
    float*  h2     = (float*)(wsb + OFF_H2);

    hipMemsetAsync(hist, 0, 200000u, stream);

    prep<<<(N_EDGES + 255) / 256, 256, 0, stream>>>(dst, hist);
    scan1<<<SCAN_NB, 256, 0, stream>>>(hist, offs, bsum, dinv);
    scan2<<<1, 256, 0, stream>>>(bsum, boff);
    scan3<<<SCAN_NB, 256, 0, stream>>>(offs, boff, cursor, hist, sorted,
                                       (unsigned short*)xsh1, (unsigned short*)xsh2);
    reorder<<<N_EDGES / 256, 256, 0, stream>>>(src, dst, cursor, sorted, N_EDGES);

    // layer 1 GEMM: 128 -> 64 (fp16 table out)
    gemm1<<<N_NODES / 16, 256, 0, stream>>>(x, W1, dinv, xsh1);
    // layer 1 aggregate + relu + fused layer-2 GEMM -> xsh2 (fp16)
    gather_f<true><<<N_NODES / 4, 256, 0, stream>>>(xsh1, offs, sorted, dinv, b1, W2, xsh2, nullptr);
    // layer 2 aggregate + relu -> h2 (fp32)
    gather_f<false><<<N_NODES / 4, 256, 0, stream>>>(xsh2, offs, sorted, dinv, b2, nullptr, nullptr, h2);

    // pool + head (batch sorted -> contiguous segments; no atomics)
    pool_head<<<N_GRAPHS, 256, 0, stream>>>(h2, batch, Wfc, bfc, y, out);
}